// Round 9
// baseline (183.033 us; speedup 1.0000x reference)
//
#include <hip/hip_runtime.h>
#include <hip/hip_bf16.h>
#include <math.h>

typedef short bf16x8 __attribute__((ext_vector_type(8)));   // 8 bf16 in 4 VGPRs
typedef float f32x16 __attribute__((ext_vector_type(16)));  // 32x32 MFMA acc

#define NB 8192
#define ND 256
#define NCLSR 100         // label values 0..99
#define BK 64             // K-chunk staged in LDS per iteration
#define INV_T 20.0f       // 1/TEMPERATURE
#define LOG2E_T 28.853900817779268f   // 20*log2(e): exp(20x) = 2^(x*this)
#define SELF_TERM 4.85165195e8f       // exp(20)

// scal[] layout: [0]=possum [1]=SL [2]=RL [3]=NH [4]=NT [5]=done-counter(int)

// ---------------- Kernel 1: row L2-normalize -> bf16 copy; zero accumulators --------
__global__ __launch_bounds__(256) void normalize_kernel(
    const float* __restrict__ feat, unsigned short* __restrict__ fb,
    float* __restrict__ hsum, float* __restrict__ nhighf,
    float* __restrict__ scal) {
    const int wave = threadIdx.x >> 6;
    const int lane = threadIdx.x & 63;
    const int row  = blockIdx.x * 4 + wave;
    float4 v = reinterpret_cast<const float4*>(feat + (size_t)row * ND)[lane];
    float ss = v.x * v.x + v.y * v.y + v.z * v.z + v.w * v.w;
    #pragma unroll
    for (int off = 32; off > 0; off >>= 1) ss += __shfl_xor(ss, off);
    const float inv = rsqrtf(ss);
    ushort4 o;
    __hip_bfloat16 h0 = __float2bfloat16(v.x * inv); o.x = *reinterpret_cast<unsigned short*>(&h0);
    __hip_bfloat16 h1 = __float2bfloat16(v.y * inv); o.y = *reinterpret_cast<unsigned short*>(&h1);
    __hip_bfloat16 h2 = __float2bfloat16(v.z * inv); o.z = *reinterpret_cast<unsigned short*>(&h2);
    __hip_bfloat16 h3 = __float2bfloat16(v.w * inv); o.w = *reinterpret_cast<unsigned short*>(&h3);
    reinterpret_cast<ushort4*>(fb + (size_t)row * ND)[lane] = o;
    if (blockIdx.x < 32) {
        const int i = (blockIdx.x << 8) + threadIdx.x;
        hsum[i] = 0.f;
        nhighf[i] = 0.f;
    } else if (blockIdx.x == 32 && threadIdx.x < 6) {
        scal[threadIdx.x] = 0.f;           // int 0 == float 0 bit pattern
    }
}

// ---------------- Kernel 2: triangular sim tiles, 8 waves, 32x32x16 MFMA ----------
// 2080 blocks = lower triangle (bi >= bj). Block: 512 threads = 8 waves; 128x128
// tile; wave tile 64x32 as 2x1 frags of v_mfma_f32_32x32x16_bf16 (32 acc regs).
// __launch_bounds__(512, 2): cap 256 regs/wave >= the kernel's ~160-reg natural
// demand -> NO spill (R7/R8's 139-410 MB WRITE_SIZE was forced spill: min-waves
// >=4 caps at 128 < 160 natural; allocator spills exactly the deficit).
// BK=64 staging via global_load_lds width-16, XOR-granule swizzle in the GLOBAL
// address. Row/col exp-sum partials -> Q slots (plain stores), positive-pair cos
// -> one atomicAdd per block. wave w: wy=w>>2 rows [wy*64,+64), wx=w&3 cols
// [wx*32,+32); w also stages rows [w*16,+16) of A and B.
__global__ __launch_bounds__(512, 2) void sim_kernel(
    const unsigned short* __restrict__ fb, const int* __restrict__ labels,
    float* __restrict__ Q, float* __restrict__ hsum,
    float* __restrict__ nhighf, float* __restrict__ scal) {
    __shared__ __align__(16) unsigned short ldsA[128 * BK];   // 16 KB
    __shared__ __align__(16) unsigned short ldsB[128 * BK];   // 16 KB
    __shared__ float ldsRow[4][128];       // [wx][local row] partial row sums
    __shared__ float ldsCol[2][128];       // [wy][local col] partial col sums
    __shared__ int   ldsLab[256];          // [0..127]=row labels, [128..255]=col labels
    __shared__ float ldsP[8];              // per-wave possum partials

    // triangular decode: t -> (bi, bj), bi >= bj
    const int t = blockIdx.x;
    int bi = (int)((sqrtf((float)(8 * t + 1)) - 1.0f) * 0.5f);
    while ((bi + 1) * (bi + 2) / 2 <= t) ++bi;
    while (bi * (bi + 1) / 2 > t) --bi;
    const int bj = t - bi * (bi + 1) / 2;
    const int I0 = bi << 7;
    const int J0 = bj << 7;
    const bool isdiag = (bi == bj);

    const int tid  = threadIdx.x;
    const int wave = tid >> 6;
    const int lane = tid & 63;
    const int wy = wave >> 2;              // 0..1 : row half
    const int wx = wave & 3;               // 0..3 : col quarter
    const int l31  = lane & 31;
    const int half = lane >> 5;

    if (tid < 128) ldsLab[tid] = labels[I0 + tid];
    else if (tid < 256) ldsLab[tid] = labels[J0 + tid - 128];

    // staging offsets: wave stages rows [w*16, +16); chunk c: Lg=(c<<6)+lane,
    // row_loc = w*16 + (Lg>>3), swizzled granule g = (Lg&7)^((Lg>>3)&7)
    int offRC[2];
    #pragma unroll
    for (int c = 0; c < 2; ++c) {
        const int Lg = (c << 6) + lane;
        const int row_loc = (wave << 4) + (Lg >> 3);
        const int g = (Lg & 7) ^ ((Lg >> 3) & 7);
        offRC[c] = row_loc * ND + (g << 3);
    }
    const unsigned short* baseA = fb + (size_t)I0 * ND;
    const unsigned short* baseB = fb + (size_t)J0 * ND;

    f32x16 acc[2];
    #pragma unroll
    for (int fy = 0; fy < 2; ++fy)
        #pragma unroll
        for (int e = 0; e < 16; ++e) acc[fy][e] = 0.f;

    for (int kk = 0; kk < ND; kk += BK) {
        __syncthreads();                   // protect LDS from prior-iter readers
        #pragma unroll
        for (int c = 0; c < 2; ++c) {
            __builtin_amdgcn_global_load_lds(
                (const __attribute__((address_space(1))) void*)(baseA + offRC[c] + kk),
                (__attribute__((address_space(3))) void*)(ldsA + (wave << 10) + (c << 9)),
                16, 0, 0);
            __builtin_amdgcn_global_load_lds(
                (const __attribute__((address_space(1))) void*)(baseB + offRC[c] + kk),
                (__attribute__((address_space(3))) void*)(ldsB + (wave << 10) + (c << 9)),
                16, 0, 0);
        }
        __syncthreads();                   // staging visible

        #pragma unroll
        for (int s = 0; s < 4; ++s) {      // four k-steps of 16 within BK=64
            // granule q = s*2+half, phys slot = q ^ (row&7); row&7 == l31&7
            const int gp = ((s << 1) + half) ^ (l31 & 7);
            const int rowB = (wx << 5) + l31;
            bf16x8 b = *reinterpret_cast<const bf16x8*>(ldsB + rowB * BK + (gp << 3));
            bf16x8 a[2];
            #pragma unroll
            for (int fy = 0; fy < 2; ++fy) {
                const int rowA = (wy << 6) + (fy << 5) + l31;
                a[fy] = *reinterpret_cast<const bf16x8*>(ldsA + rowA * BK + (gp << 3));
            }
            #pragma unroll
            for (int fy = 0; fy < 2; ++fy)
                acc[fy] = __builtin_amdgcn_mfma_f32_32x32x16_bf16(a[fy], b, acc[fy], 0, 0, 0);
        }
    }

    // Epilogue. C/D layout (m74/m101-verified, R7/R8-validated): col = l31,
    // row = (reg&3) + 8*(reg>>2) + 4*half.
    const int cb = J0 + (wx << 5);
    const int lcol = ldsLab[128 + (wx << 5) + l31];   // this lane's column label

    int anyhigh = 0;
    float cs = 0.f;                        // col partial (this lane's col)
    float pp = 0.f;                        // positive-pair cos partial
    #pragma unroll
    for (int fy = 0; fy < 2; ++fy) {
        const bool dband = isdiag && (((wy << 1) + fy) == wx);
        #pragma unroll
        for (int reg = 0; reg < 16; ++reg) {
            const int rloc = (reg & 3) + ((reg >> 2) << 3) + (half << 2);  // 0..31
            const int row_local = (wy << 6) + (fy << 5) + rloc;
            const int lrow = ldsLab[row_local];
            const float a = acc[fy][reg];
            const bool diag_el = dband && (l31 == rloc);
            float e = exp2f(a * LOG2E_T);
            if (diag_el) e = 0.f;
            cs += e;
            if (lcol == lrow && !diag_el) pp += a;
            anyhigh |= (!diag_el && a > 0.7f);
            float d = e;
            #pragma unroll
            for (int off = 16; off > 0; off >>= 1) d += __shfl_xor(d, off);
            if (l31 == 0)
                ldsRow[wx][row_local] = d;
        }
    }
    cs += __shfl_xor(cs, 32);              // combine halves (same column)
    if (half == 0 && !isdiag)
        ldsCol[wy][(wx << 5) + l31] = cs;
    #pragma unroll
    for (int off = 32; off > 0; off >>= 1) pp += __shfl_xor(pp, off);
    if (lane == 0) ldsP[wave] = pp;

    __syncthreads();
    if (tid < 128) {
        Q[(size_t)(bi * 64 + bj) * 128 + tid] =
            ldsRow[0][tid] + ldsRow[1][tid] + ldsRow[2][tid] + ldsRow[3][tid];
    } else if (tid < 256 && !isdiag) {
        const int c2 = tid - 128;
        Q[(size_t)(bj * 64 + bi) * 128 + c2] = ldsCol[0][c2] + ldsCol[1][c2];
    }
    if (tid == 0) {
        const float scale = isdiag ? 1.f : 2.f;
        atomicAdd(&scal[0], (ldsP[0] + ldsP[1] + ldsP[2] + ldsP[3] +
                             ldsP[4] + ldsP[5] + ldsP[6] + ldsP[7]) * scale);
    }

    // Cold path: some off-diag element had cos > 0.7 -> relax-term bookkeeping.
    if (__any(anyhigh)) {
        float hc = 0.f, nc = 0.f;
        #pragma unroll
        for (int fy = 0; fy < 2; ++fy) {
            const bool dband = isdiag && (((wy << 1) + fy) == wx);
            #pragma unroll
            for (int reg = 0; reg < 16; ++reg) {
                const int rloc = (reg & 3) + ((reg >> 2) << 3) + (half << 2);
                const int row_local = (wy << 6) + (fy << 5) + rloc;
                const int lrow = ldsLab[row_local];
                const float a = acc[fy][reg];
                const bool diag_el = dband && (l31 == rloc);
                float hs = 0.f, nh = 0.f;
                if (a > 0.7f && lcol == lrow && !diag_el) {
                    const float e = exp2f(a * LOG2E_T);
                    hs = e; nh = 1.f;
                    hc += e; nc += 1.f;
                }
                #pragma unroll
                for (int off = 16; off > 0; off >>= 1) {
                    hs += __shfl_xor(hs, off);
                    nh += __shfl_xor(nh, off);
                }
                if (l31 == 0 && nh > 0.f) {
                    atomicAdd(&hsum[I0 + row_local], hs);
                    atomicAdd(&nhighf[I0 + row_local], nh);
                }
            }
        }
        if (!isdiag) {
            hc += __shfl_xor(hc, 32);
            nc += __shfl_xor(nc, 32);
            if (half == 0 && nc > 0.f) {
                atomicAdd(&hsum[cb + l31], hc);
                atomicAdd(&nhighf[cb + l31], nc);
            }
        }
    }
}

// ---------------- Kernel 3: fused Q-reduce + finalize (64 blocks) ----------------
// Block g reduces Q for rows [128g,+128) -> denom in LDS, builds the label
// histogram in LDS, computes its partial SL/RL/NH (block 0: NT), atomicAdds into
// scal[1..4], then the last block (ticket 63) composes out[0].
__global__ __launch_bounds__(256) void finalize_kernel(
    const float* __restrict__ Q, const float* __restrict__ hsum,
    const float* __restrict__ nhighf, const int* __restrict__ labels,
    float* __restrict__ scal, float* __restrict__ out) {
    const int g = blockIdx.x;
    const int tid = threadIdx.x;
    __shared__ int cnt[128];
    if (tid < 128) cnt[tid] = 0;
    __syncthreads();
    for (int i = tid; i < NB; i += 256)
        atomicAdd(&cnt[labels[i]], 1);
    // denom for row r of this block's 128 rows: sum of 64 Q slots
    const int r = tid & 127;
    const int sh = tid >> 7;
    const float* base = Q + (size_t)g * 64 * 128;
    float s = 0.f;
    #pragma unroll 8
    for (int i = 0; i < 32; ++i)
        s += base[(size_t)(sh * 32 + i) * 128 + r];
    __shared__ float red[256];
    red[tid] = s;
    __syncthreads();
    float SL = 0.f, RL = 0.f, NH = 0.f, NT = 0.f;
    if (tid < 128) {
        const float denom = red[tid] + red[tid + 128];
        const int i = (g << 7) + tid;
        const float np = (float)(cnt[labels[i]] - 1);
        SL = np * logf(denom + 1e-8f);
        const float h = hsum[i];
        if (h > 0.f) RL = logf(h + SELF_TERM);
        NH = nhighf[i];
    }
    if (g == 0 && tid < NCLSR) {
        const float nc = (float)cnt[tid];
        NT = nc * (nc - 1.f);
    }
    #pragma unroll
    for (int off = 32; off > 0; off >>= 1) {
        SL += __shfl_xor(SL, off); RL += __shfl_xor(RL, off);
        NH += __shfl_xor(NH, off); NT += __shfl_xor(NT, off);
    }
    __shared__ float part[4][4];
    if ((tid & 63) == 0) {
        int w = tid >> 6;
        part[w][0] = SL; part[w][1] = RL; part[w][2] = NH; part[w][3] = NT;
    }
    __syncthreads();
    if (tid == 0) {
        float sl = part[0][0] + part[1][0] + part[2][0] + part[3][0];
        float rl = part[0][1] + part[1][1] + part[2][1] + part[3][1];
        float nh = part[0][2] + part[1][2] + part[2][2] + part[3][2];
        float nt = part[0][3] + part[1][3] + part[2][3] + part[3][3];
        atomicAdd(&scal[1], sl);
        atomicAdd(&scal[2], rl);
        atomicAdd(&scal[3], nh);
        if (g == 0) atomicAdd(&scal[4], nt);
        __threadfence();
        const int ticket = atomicAdd((int*)(scal + 5), 1);
        if (ticket == 63) {
            const float SLt = atomicAdd(&scal[1], 0.f);
            const float RLt = atomicAdd(&scal[2], 0.f);
            const float NHt = atomicAdd(&scal[3], 0.f);
            const float NTt = atomicAdd(&scal[4], 0.f);
            const float pos = atomicAdd(&scal[0], 0.f) * INV_T;
            const float scl   = (NTt > 0.f) ? (SLt - pos) / NTt : 0.f;
            const float relax = (NHt > 0.f) ? RLt / NHt : 0.f;
            out[0] = scl + relax;
        }
    }
}

extern "C" void kernel_launch(void* const* d_in, const int* in_sizes, int n_in,
                              void* d_out, int out_size, void* d_ws, size_t ws_size,
                              hipStream_t stream) {
    const float* feat  = (const float*)d_in[0];
    const int* labels  = (const int*)d_in[1];
    float* out = (float*)d_out;

    char* ws = (char*)d_ws;
    unsigned short* fb = (unsigned short*)ws;                                // 4 MB
    float* Q      = (float*)(ws + (size_t)NB * ND * sizeof(unsigned short)); // 2 MB
    float* hsum   = Q + 64 * 64 * 128;
    float* nhighf = hsum + NB;
    float* scal   = nhighf + NB;          // 6 floats: possum,SL,RL,NH,NT,done

    normalize_kernel<<<NB / 4, 256, 0, stream>>>(feat, fb, hsum, nhighf, scal);
    sim_kernel<<<2080, 512, 0, stream>>>(fb, labels, Q, hsum, nhighf, scal);
    finalize_kernel<<<64, 256, 0, stream>>>(Q, hsum, nhighf, labels, scal, out);
}

// Round 10
// 142.821 us; speedup vs baseline: 1.2816x; 1.2816x over previous
//
#include <hip/hip_runtime.h>
#include <hip/hip_bf16.h>
#include <math.h>

typedef short bf16x8 __attribute__((ext_vector_type(8)));   // 8 bf16 in 4 VGPRs
typedef float f32x16 __attribute__((ext_vector_type(16)));  // 32x32 MFMA acc

#define NB 8192
#define ND 256
#define NCLSR 100         // label values 0..99
#define BK 64             // K-chunk staged in LDS per iteration
#define INV_T 20.0f       // 1/TEMPERATURE
#define LOG2E_T 28.853900817779268f   // 20*log2(e): exp(20x) = 2^(x*this)
#define SELF_TERM 4.85165195e8f       // exp(20)

// scal[] layout: [0]=possum [1]=SL [2]=RL [3]=NH [4]=NT [5]=done-counter(int)

// ---------------- Kernel 1: row L2-normalize -> bf16 copy; zero accumulators --------
__global__ __launch_bounds__(256) void normalize_kernel(
    const float* __restrict__ feat, unsigned short* __restrict__ fb,
    float* __restrict__ hsum, float* __restrict__ nhighf,
    float* __restrict__ scal) {
    const int wave = threadIdx.x >> 6;
    const int lane = threadIdx.x & 63;
    const int row  = blockIdx.x * 4 + wave;
    float4 v = reinterpret_cast<const float4*>(feat + (size_t)row * ND)[lane];
    float ss = v.x * v.x + v.y * v.y + v.z * v.z + v.w * v.w;
    #pragma unroll
    for (int off = 32; off > 0; off >>= 1) ss += __shfl_xor(ss, off);
    const float inv = rsqrtf(ss);
    ushort4 o;
    __hip_bfloat16 h0 = __float2bfloat16(v.x * inv); o.x = *reinterpret_cast<unsigned short*>(&h0);
    __hip_bfloat16 h1 = __float2bfloat16(v.y * inv); o.y = *reinterpret_cast<unsigned short*>(&h1);
    __hip_bfloat16 h2 = __float2bfloat16(v.z * inv); o.z = *reinterpret_cast<unsigned short*>(&h2);
    __hip_bfloat16 h3 = __float2bfloat16(v.w * inv); o.w = *reinterpret_cast<unsigned short*>(&h3);
    reinterpret_cast<ushort4*>(fb + (size_t)row * ND)[lane] = o;
    if (blockIdx.x < 32) {
        const int i = (blockIdx.x << 8) + threadIdx.x;
        hsum[i] = 0.f;
        nhighf[i] = 0.f;
    } else if (blockIdx.x == 32 && threadIdx.x < 6) {
        scal[threadIdx.x] = 0.f;           // int 0 == float 0 bit pattern
    }
}

// ---------------- Kernel 2: FULL-grid sim tiles, column-sum epilogue ----------
// grid (64,64): block (bj,bi) computes tile E(I,J), I=bi*128 rows, J=bj*128 cols.
// 512 threads = 8 waves; wave tile 64x32 as 2x1 frags of v_mfma_f32_32x32x16_bf16.
// KEY CHANGE vs R9: full grid (not triangle) so the ONLY reduction needed is the
// column sum -- in the 32x32 C-layout col==lane, so each lane sums its 32 regs
// in-register (31 adds + 1 cross-half shuffle) instead of R9's 160-shuffle/lane
// row-reduce storm on the LDS pipe. E is numerically symmetric (MFMA dot(fi,fj)
// == dot(fj,fi)), so column sums of the full grid give denom exactly.
// Block writes its 128 col partials to Q[(bj*64+bi)*128+c] (plain stores);
// positive-pair cos -> one atomicAdd per block. __launch_bounds__(512,2):
// cap 256 >= natural demand -> no spill (verified R9).
__global__ __launch_bounds__(512, 2) void sim_kernel(
    const unsigned short* __restrict__ fb, const int* __restrict__ labels,
    float* __restrict__ Q, float* __restrict__ hsum,
    float* __restrict__ nhighf, float* __restrict__ scal) {
    __shared__ __align__(16) unsigned short ldsA[128 * BK];   // 16 KB
    __shared__ __align__(16) unsigned short ldsB[128 * BK];   // 16 KB
    __shared__ float ldsCol[2][128];       // [wy][local col] partial col sums
    __shared__ int   ldsLab[256];          // [0..127]=row labels, [128..255]=col labels
    __shared__ float ldsP[8];              // per-wave possum partials

    const int bj = blockIdx.x;
    const int bi = blockIdx.y;
    const int I0 = bi << 7;
    const int J0 = bj << 7;
    const bool isdiag = (bi == bj);

    const int tid  = threadIdx.x;
    const int wave = tid >> 6;
    const int lane = tid & 63;
    const int wy = wave >> 2;              // 0..1 : row half
    const int wx = wave & 3;               // 0..3 : col quarter
    const int l31  = lane & 31;
    const int half = lane >> 5;

    if (tid < 128) ldsLab[tid] = labels[I0 + tid];
    else if (tid < 256) ldsLab[tid] = labels[J0 + tid - 128];

    // staging offsets: wave stages rows [w*16, +16); chunk c: Lg=(c<<6)+lane,
    // row_loc = w*16 + (Lg>>3), swizzled granule g = (Lg&7)^((Lg>>3)&7)
    int offRC[2];
    #pragma unroll
    for (int c = 0; c < 2; ++c) {
        const int Lg = (c << 6) + lane;
        const int row_loc = (wave << 4) + (Lg >> 3);
        const int g = (Lg & 7) ^ ((Lg >> 3) & 7);
        offRC[c] = row_loc * ND + (g << 3);
    }
    const unsigned short* baseA = fb + (size_t)I0 * ND;
    const unsigned short* baseB = fb + (size_t)J0 * ND;

    f32x16 acc[2];
    #pragma unroll
    for (int fy = 0; fy < 2; ++fy)
        #pragma unroll
        for (int e = 0; e < 16; ++e) acc[fy][e] = 0.f;

    for (int kk = 0; kk < ND; kk += BK) {
        __syncthreads();                   // protect LDS from prior-iter readers
        #pragma unroll
        for (int c = 0; c < 2; ++c) {
            __builtin_amdgcn_global_load_lds(
                (const __attribute__((address_space(1))) void*)(baseA + offRC[c] + kk),
                (__attribute__((address_space(3))) void*)(ldsA + (wave << 10) + (c << 9)),
                16, 0, 0);
            __builtin_amdgcn_global_load_lds(
                (const __attribute__((address_space(1))) void*)(baseB + offRC[c] + kk),
                (__attribute__((address_space(3))) void*)(ldsB + (wave << 10) + (c << 9)),
                16, 0, 0);
        }
        __syncthreads();                   // staging visible

        #pragma unroll
        for (int s = 0; s < 4; ++s) {      // four k-steps of 16 within BK=64
            // granule q = s*2+half, phys slot = q ^ (row&7); row&7 == l31&7
            const int gp = ((s << 1) + half) ^ (l31 & 7);
            const int rowB = (wx << 5) + l31;
            bf16x8 b = *reinterpret_cast<const bf16x8*>(ldsB + rowB * BK + (gp << 3));
            bf16x8 a[2];
            #pragma unroll
            for (int fy = 0; fy < 2; ++fy) {
                const int rowA = (wy << 6) + (fy << 5) + l31;
                a[fy] = *reinterpret_cast<const bf16x8*>(ldsA + rowA * BK + (gp << 3));
            }
            #pragma unroll
            for (int fy = 0; fy < 2; ++fy)
                acc[fy] = __builtin_amdgcn_mfma_f32_32x32x16_bf16(a[fy], b, acc[fy], 0, 0, 0);
        }
    }

    // Epilogue. C/D layout (m74/m101-verified, R7-R9-validated): col = l31,
    // row = (reg&3) + 8*(reg>>2) + 4*half. Column sums are per-lane in-register.
    const int lcol = ldsLab[128 + (wx << 5) + l31];   // this lane's column label

    int anyhigh = 0;
    float cs = 0.f;                        // col partial (this lane's col, 64 rows)
    float pp = 0.f;                        // positive-pair cos partial
    #pragma unroll
    for (int fy = 0; fy < 2; ++fy) {
        const bool dband = isdiag && (((wy << 1) + fy) == wx);
        #pragma unroll
        for (int reg = 0; reg < 16; ++reg) {
            const int rloc = (reg & 3) + ((reg >> 2) << 3) + (half << 2);  // 0..31
            const int lrow = ldsLab[(wy << 6) + (fy << 5) + rloc];
            const float a = acc[fy][reg];
            const bool diag_el = dband && (l31 == rloc);
            float e = exp2f(a * LOG2E_T);
            if (diag_el) e = 0.f;
            cs += e;
            if (lcol == lrow && !diag_el) pp += a;
            anyhigh |= (!diag_el && a > 0.7f);
        }
    }
    cs += __shfl_xor(cs, 32);              // combine halves (same column)
    if (half == 0) ldsCol[wy][(wx << 5) + l31] = cs;
    #pragma unroll
    for (int off = 32; off > 0; off >>= 1) pp += __shfl_xor(pp, off);
    if (lane == 0) ldsP[wave] = pp;

    __syncthreads();
    if (tid < 128)
        Q[(size_t)(bj * 64 + bi) * 128 + tid] = ldsCol[0][tid] + ldsCol[1][tid];
    if (tid == 0)
        atomicAdd(&scal[0], ldsP[0] + ldsP[1] + ldsP[2] + ldsP[3] +
                            ldsP[4] + ldsP[5] + ldsP[6] + ldsP[7]);

    // Cold path: some off-diag element had cos > 0.7 -> relax-term bookkeeping.
    // Full grid sees each ordered pair exactly once -> direct per-element atomics.
    if (__any(anyhigh)) {
        #pragma unroll
        for (int fy = 0; fy < 2; ++fy) {
            const bool dband = isdiag && (((wy << 1) + fy) == wx);
            #pragma unroll
            for (int reg = 0; reg < 16; ++reg) {
                const int rloc = (reg & 3) + ((reg >> 2) << 3) + (half << 2);
                const int row_local = (wy << 6) + (fy << 5) + rloc;
                const int lrow = ldsLab[row_local];
                const float a = acc[fy][reg];
                const bool diag_el = dband && (l31 == rloc);
                if (a > 0.7f && lcol == lrow && !diag_el) {
                    atomicAdd(&hsum[I0 + row_local], exp2f(a * LOG2E_T));
                    atomicAdd(&nhighf[I0 + row_local], 1.f);
                }
            }
        }
    }
}

// ---------------- Kernel 3: fused Q-reduce + finalize (64 blocks) ----------------
// Block g reduces Q for denom rows [128g,+128), builds the label histogram in
// LDS, computes its partial SL/RL/NH (block 0: NT), atomicAdds into scal[1..4];
// the last block (ticket 63) composes out[0].
__global__ __launch_bounds__(256) void finalize_kernel(
    const float* __restrict__ Q, const float* __restrict__ hsum,
    const float* __restrict__ nhighf, const int* __restrict__ labels,
    float* __restrict__ scal, float* __restrict__ out) {
    const int g = blockIdx.x;
    const int tid = threadIdx.x;
    __shared__ int cnt[128];
    if (tid < 128) cnt[tid] = 0;
    __syncthreads();
    for (int i = tid; i < NB; i += 256)
        atomicAdd(&cnt[labels[i]], 1);
    // denom for row r of this block's 128 rows: sum of 64 Q slots
    const int r = tid & 127;
    const int sh = tid >> 7;
    const float* base = Q + (size_t)g * 64 * 128;
    float s = 0.f;
    #pragma unroll 8
    for (int i = 0; i < 32; ++i)
        s += base[(size_t)(sh * 32 + i) * 128 + r];
    __shared__ float red[256];
    red[tid] = s;
    __syncthreads();
    float SL = 0.f, RL = 0.f, NH = 0.f, NT = 0.f;
    if (tid < 128) {
        const float denom = red[tid] + red[tid + 128];
        const int i = (g << 7) + tid;
        const float np = (float)(cnt[labels[i]] - 1);
        SL = np * logf(denom + 1e-8f);
        const float h = hsum[i];
        if (h > 0.f) RL = logf(h + SELF_TERM);
        NH = nhighf[i];
    }
    if (g == 0 && tid < NCLSR) {
        const float nc = (float)cnt[tid];
        NT = nc * (nc - 1.f);
    }
    #pragma unroll
    for (int off = 32; off > 0; off >>= 1) {
        SL += __shfl_xor(SL, off); RL += __shfl_xor(RL, off);
        NH += __shfl_xor(NH, off); NT += __shfl_xor(NT, off);
    }
    __shared__ float part[4][4];
    if ((tid & 63) == 0) {
        int w = tid >> 6;
        part[w][0] = SL; part[w][1] = RL; part[w][2] = NH; part[w][3] = NT;
    }
    __syncthreads();
    if (tid == 0) {
        float sl = part[0][0] + part[1][0] + part[2][0] + part[3][0];
        float rl = part[0][1] + part[1][1] + part[2][1] + part[3][1];
        float nh = part[0][2] + part[1][2] + part[2][2] + part[3][2];
        float nt = part[0][3] + part[1][3] + part[2][3] + part[3][3];
        atomicAdd(&scal[1], sl);
        atomicAdd(&scal[2], rl);
        atomicAdd(&scal[3], nh);
        if (g == 0) atomicAdd(&scal[4], nt);
        __threadfence();
        const int ticket = atomicAdd((int*)(scal + 5), 1);
        if (ticket == 63) {
            const float SLt = atomicAdd(&scal[1], 0.f);
            const float RLt = atomicAdd(&scal[2], 0.f);
            const float NHt = atomicAdd(&scal[3], 0.f);
            const float NTt = atomicAdd(&scal[4], 0.f);
            const float pos = atomicAdd(&scal[0], 0.f) * INV_T;
            const float scl   = (NTt > 0.f) ? (SLt - pos) / NTt : 0.f;
            const float relax = (NHt > 0.f) ? RLt / NHt : 0.f;
            out[0] = scl + relax;
        }
    }
}

extern "C" void kernel_launch(void* const* d_in, const int* in_sizes, int n_in,
                              void* d_out, int out_size, void* d_ws, size_t ws_size,
                              hipStream_t stream) {
    const float* feat  = (const float*)d_in[0];
    const int* labels  = (const int*)d_in[1];
    float* out = (float*)d_out;

    char* ws = (char*)d_ws;
    unsigned short* fb = (unsigned short*)ws;                                // 4 MB
    float* Q      = (float*)(ws + (size_t)NB * ND * sizeof(unsigned short)); // 2 MB
    float* hsum   = Q + 64 * 64 * 128;
    float* nhighf = hsum + NB;
    float* scal   = nhighf + NB;          // 6 floats: possum,SL,RL,NH,NT,done

    normalize_kernel<<<NB / 4, 256, 0, stream>>>(feat, fb, hsum, nhighf, scal);
    sim_kernel<<<dim3(64, 64), 512, 0, stream>>>(fb, labels, Q, hsum, nhighf, scal);
    finalize_kernel<<<64, 256, 0, stream>>>(Q, hsum, nhighf, labels, scal, out);
}

// Round 11
// 122.120 us; speedup vs baseline: 1.4988x; 1.1695x over previous
//
#include <hip/hip_runtime.h>
#include <hip/hip_bf16.h>
#include <math.h>

typedef short bf16x8 __attribute__((ext_vector_type(8)));   // 8 bf16 in 4 VGPRs
typedef float f32x16 __attribute__((ext_vector_type(16)));  // 32x32 MFMA acc

#define NB 8192
#define ND 256
#define NCLSR 100         // label values 0..99
#define BK 64             // K-chunk staged in LDS per iteration
#define INV_T 20.0f       // 1/TEMPERATURE
#define LOG2E_T 28.853900817779268f   // 20*log2(e): exp(20x) = 2^(x*this)
#define SELF_TERM 4.85165195e8f       // exp(20)

// scal[] layout: [0]=possum [1]=SL [2]=RL [3]=NH [4]=NT [5]=done-counter(int)

// ---------------- Kernel 1: row L2-normalize -> bf16 copy; zero accumulators --------
__global__ __launch_bounds__(256) void normalize_kernel(
    const float* __restrict__ feat, unsigned short* __restrict__ fb,
    float* __restrict__ hsum, float* __restrict__ nhighf,
    float* __restrict__ scal) {
    const int wave = threadIdx.x >> 6;
    const int lane = threadIdx.x & 63;
    const int row  = blockIdx.x * 4 + wave;
    float4 v = reinterpret_cast<const float4*>(feat + (size_t)row * ND)[lane];
    float ss = v.x * v.x + v.y * v.y + v.z * v.z + v.w * v.w;
    #pragma unroll
    for (int off = 32; off > 0; off >>= 1) ss += __shfl_xor(ss, off);
    const float inv = rsqrtf(ss);
    ushort4 o;
    __hip_bfloat16 h0 = __float2bfloat16(v.x * inv); o.x = *reinterpret_cast<unsigned short*>(&h0);
    __hip_bfloat16 h1 = __float2bfloat16(v.y * inv); o.y = *reinterpret_cast<unsigned short*>(&h1);
    __hip_bfloat16 h2 = __float2bfloat16(v.z * inv); o.z = *reinterpret_cast<unsigned short*>(&h2);
    __hip_bfloat16 h3 = __float2bfloat16(v.w * inv); o.w = *reinterpret_cast<unsigned short*>(&h3);
    reinterpret_cast<ushort4*>(fb + (size_t)row * ND)[lane] = o;
    if (blockIdx.x < 32) {
        const int i = (blockIdx.x << 8) + threadIdx.x;
        hsum[i] = 0.f;
        nhighf[i] = 0.f;
    } else if (blockIdx.x == 32 && threadIdx.x < 6) {
        scal[threadIdx.x] = 0.f;           // int 0 == float 0 bit pattern
    }
}

// ---------------- Kernel 2: TRIANGULAR sim tiles, MFMA row-sum epilogue ----------
// 2080 blocks = lower triangle (bi >= bj). 512 threads = 8 waves; 128x128 tile;
// wave tile 64x32 as 2x1 frags of v_mfma_f32_32x32x16_bf16 (col-sum is free:
// col==lane, in-register adds).  ROW sums (needed for the mirror slot) via a
// SECOND MFMA: E=exp(tile) stored bf16 into LDS (overlaying the dead staging
// buffers), then D = ones * E_B with the B-operand gathered row-major exactly
// like the K-loop's b-frags -> lane l31 holds rowsum(E row 32w+l31) replicated
// across regs; extraction is one store/lane (replaces R9's 160-shuffle/lane
// storm that made the triangle lose to the full grid).
// Q: row sums -> slot [bi][bj], col sums -> mirror slot [bj][bi]; 2080+2016 =
// 4096 slots each written once (plain stores). possum: x2 on off-diag tiles.
// __launch_bounds__(512,2): cap 256 >= natural demand -> no spill (R9/R10).
__global__ __launch_bounds__(512, 2) void sim_kernel(
    const unsigned short* __restrict__ fb, const int* __restrict__ labels,
    float* __restrict__ Q, float* __restrict__ hsum,
    float* __restrict__ nhighf, float* __restrict__ scal) {
    __shared__ __align__(16) unsigned short ldsAB[2 * 128 * BK]; // 32 KB: A|B, overlaid by E
    __shared__ float ldsCol[2][128];       // [wy][local col] partial col sums
    __shared__ float ldsRowF[128];         // full row sums (from MFMA trick)
    __shared__ int   ldsLab[256];          // [0..127]=row labels, [128..255]=col labels
    __shared__ float ldsP[8];              // per-wave possum partials
    unsigned short* ldsA = ldsAB;
    unsigned short* ldsB = ldsAB + 128 * BK;
    unsigned short* ldsE = ldsAB;          // 128x128 bf16 = 32 KB overlay

    // triangular decode: t -> (bi, bj), bi >= bj  (validated R5-R9)
    const int t = blockIdx.x;
    int bi = (int)((sqrtf((float)(8 * t + 1)) - 1.0f) * 0.5f);
    while ((bi + 1) * (bi + 2) / 2 <= t) ++bi;
    while (bi * (bi + 1) / 2 > t) --bi;
    const int bj = t - bi * (bi + 1) / 2;
    const int I0 = bi << 7;
    const int J0 = bj << 7;
    const bool isdiag = (bi == bj);

    const int tid  = threadIdx.x;
    const int wave = tid >> 6;
    const int lane = tid & 63;
    const int wy = wave >> 2;              // 0..1 : row half
    const int wx = wave & 3;               // 0..3 : col quarter
    const int l31  = lane & 31;
    const int half = lane >> 5;

    if (tid < 128) ldsLab[tid] = labels[I0 + tid];
    else if (tid < 256) ldsLab[tid] = labels[J0 + tid - 128];

    // staging offsets: wave stages rows [w*16, +16); chunk c: Lg=(c<<6)+lane,
    // row_loc = w*16 + (Lg>>3), swizzled granule g = (Lg&7)^((Lg>>3)&7)
    int offRC[2];
    #pragma unroll
    for (int c = 0; c < 2; ++c) {
        const int Lg = (c << 6) + lane;
        const int row_loc = (wave << 4) + (Lg >> 3);
        const int g = (Lg & 7) ^ ((Lg >> 3) & 7);
        offRC[c] = row_loc * ND + (g << 3);
    }
    const unsigned short* baseA = fb + (size_t)I0 * ND;
    const unsigned short* baseB = fb + (size_t)J0 * ND;

    f32x16 acc[2];
    #pragma unroll
    for (int fy = 0; fy < 2; ++fy)
        #pragma unroll
        for (int e = 0; e < 16; ++e) acc[fy][e] = 0.f;

    for (int kk = 0; kk < ND; kk += BK) {
        __syncthreads();                   // protect LDS from prior-iter readers
        #pragma unroll
        for (int c = 0; c < 2; ++c) {
            __builtin_amdgcn_global_load_lds(
                (const __attribute__((address_space(1))) void*)(baseA + offRC[c] + kk),
                (__attribute__((address_space(3))) void*)(ldsA + (wave << 10) + (c << 9)),
                16, 0, 0);
            __builtin_amdgcn_global_load_lds(
                (const __attribute__((address_space(1))) void*)(baseB + offRC[c] + kk),
                (__attribute__((address_space(3))) void*)(ldsB + (wave << 10) + (c << 9)),
                16, 0, 0);
        }
        __syncthreads();                   // staging visible

        #pragma unroll
        for (int s = 0; s < 4; ++s) {      // four k-steps of 16 within BK=64
            const int gp = ((s << 1) + half) ^ (l31 & 7);
            const int rowB = (wx << 5) + l31;
            bf16x8 b = *reinterpret_cast<const bf16x8*>(ldsB + rowB * BK + (gp << 3));
            bf16x8 a[2];
            #pragma unroll
            for (int fy = 0; fy < 2; ++fy) {
                const int rowA = (wy << 6) + (fy << 5) + l31;
                a[fy] = *reinterpret_cast<const bf16x8*>(ldsA + rowA * BK + (gp << 3));
            }
            #pragma unroll
            for (int fy = 0; fy < 2; ++fy)
                acc[fy] = __builtin_amdgcn_mfma_f32_32x32x16_bf16(a[fy], b, acc[fy], 0, 0, 0);
        }
    }
    __syncthreads();                       // all K-loop LDS reads done before E overwrite

    // Epilogue pass 1: exp, col partials, possum, E -> LDS (bf16, XOR-granule
    // swizzled: phys granule = (c>>3) ^ (r&7), row stride 128 bf16).
    // C/D layout (m74/m101-verified): col = l31, row = (reg&3)+8*(reg>>2)+4*half.
    const int ccol = (wx << 5) + l31;      // block-local col
    const int lcol = ldsLab[128 + ccol];

    int anyhigh = 0;
    float cs = 0.f;                        // this lane's col partial (64 rows)
    float pp = 0.f;                        // positive-pair cos partial
    #pragma unroll
    for (int fy = 0; fy < 2; ++fy) {
        const bool dband = isdiag && (((wy << 1) + fy) == wx);
        #pragma unroll
        for (int reg = 0; reg < 16; ++reg) {
            const int rloc = (reg & 3) + ((reg >> 2) << 3) + (half << 2);  // 0..31
            const int row_local = (wy << 6) + (fy << 5) + rloc;
            const int lrow = ldsLab[row_local];
            const float a = acc[fy][reg];
            const bool diag_el = dband && (l31 == rloc);
            float e = exp2f(a * LOG2E_T);
            if (diag_el) e = 0.f;
            cs += e;
            if (lcol == lrow && !diag_el) pp += a;
            anyhigh |= (!diag_el && a > 0.7f);
            __hip_bfloat16 h = __float2bfloat16(e);
            const int pg = (ccol >> 3) ^ (row_local & 7);
            ldsE[row_local * 128 + (pg << 3) + (ccol & 7)] =
                *reinterpret_cast<unsigned short*>(&h);
        }
    }
    cs += __shfl_xor(cs, 32);              // combine halves (same column)
    if (half == 0) ldsCol[wy][ccol] = cs;
    #pragma unroll
    for (int off = 32; off > 0; off >>= 1) pp += __shfl_xor(pp, off);
    if (lane == 0) ldsP[wave] = pp;

    __syncthreads();                       // E complete

    // Epilogue pass 2: row sums via MFMA. Waves 0..3 handle E rows [32w,+32).
    // D = ones(A) x E(B): B-frag lane n=l31 gathers E[row 32w+l31][k-chunk]
    // (row-major, same convention as the K-loop b-frags) -> D[m][n] =
    // rowsum(E row 32w+l31), identical across regs.
    if (wave < 4) {
        bf16x8 ones;
        #pragma unroll
        for (int j = 0; j < 8; ++j) ones[j] = (short)0x3F80;   // bf16 1.0
        f32x16 rs;
        #pragma unroll
        for (int e = 0; e < 16; ++e) rs[e] = 0.f;
        const int rE = (wave << 5) + l31;
        #pragma unroll
        for (int kc = 0; kc < 8; ++kc) {
            const int pg = ((kc << 1) + half) ^ (l31 & 7);
            bf16x8 bE = *reinterpret_cast<const bf16x8*>(ldsE + rE * 128 + (pg << 3));
            rs = __builtin_amdgcn_mfma_f32_32x32x16_bf16(ones, bE, rs, 0, 0, 0);
        }
        if (half == 0) ldsRowF[rE] = rs[0];
    }
    __syncthreads();                       // ldsRowF + ldsCol ready

    if (tid < 128) {
        Q[(size_t)(bi * 64 + bj) * 128 + tid] = ldsRowF[tid];
    } else if (tid < 256 && !isdiag) {
        const int c2 = tid - 128;
        Q[(size_t)(bj * 64 + bi) * 128 + c2] = ldsCol[0][c2] + ldsCol[1][c2];
    }
    if (tid == 0) {
        const float scale = isdiag ? 1.f : 2.f;
        atomicAdd(&scal[0], (ldsP[0] + ldsP[1] + ldsP[2] + ldsP[3] +
                             ldsP[4] + ldsP[5] + ldsP[6] + ldsP[7]) * scale);
    }

    // Cold path: some off-diag element had cos > 0.7 (never for this data).
    // Triangle: each unordered pair seen once -> contribute both (i,j) and (j,i).
    if (__any(anyhigh)) {
        #pragma unroll
        for (int fy = 0; fy < 2; ++fy) {
            const bool dband = isdiag && (((wy << 1) + fy) == wx);
            #pragma unroll
            for (int reg = 0; reg < 16; ++reg) {
                const int rloc = (reg & 3) + ((reg >> 2) << 3) + (half << 2);
                const int row_local = (wy << 6) + (fy << 5) + rloc;
                const int lrow = ldsLab[row_local];
                const float a = acc[fy][reg];
                const bool diag_el = dband && (l31 == rloc);
                if (a > 0.7f && lcol == lrow && !diag_el) {
                    const float e2 = exp2f(a * LOG2E_T);
                    atomicAdd(&hsum[I0 + row_local], e2);
                    atomicAdd(&nhighf[I0 + row_local], 1.f);
                    if (!isdiag) {
                        atomicAdd(&hsum[J0 + ccol], e2);
                        atomicAdd(&nhighf[J0 + ccol], 1.f);
                    }
                }
            }
        }
    }
}

// ---------------- Kernel 3: fused Q-reduce + finalize (64 blocks) ----------------
__global__ __launch_bounds__(256) void finalize_kernel(
    const float* __restrict__ Q, const float* __restrict__ hsum,
    const float* __restrict__ nhighf, const int* __restrict__ labels,
    float* __restrict__ scal, float* __restrict__ out) {
    const int g = blockIdx.x;
    const int tid = threadIdx.x;
    __shared__ int cnt[128];
    if (tid < 128) cnt[tid] = 0;
    __syncthreads();
    for (int i = tid; i < NB; i += 256)
        atomicAdd(&cnt[labels[i]], 1);
    const int r = tid & 127;
    const int sh = tid >> 7;
    const float* base = Q + (size_t)g * 64 * 128;
    float s = 0.f;
    #pragma unroll 8
    for (int i = 0; i < 32; ++i)
        s += base[(size_t)(sh * 32 + i) * 128 + r];
    __shared__ float red[256];
    red[tid] = s;
    __syncthreads();
    float SL = 0.f, RL = 0.f, NH = 0.f, NT = 0.f;
    if (tid < 128) {
        const float denom = red[tid] + red[tid + 128];
        const int i = (g << 7) + tid;
        const float np = (float)(cnt[labels[i]] - 1);
        SL = np * logf(denom + 1e-8f);
        const float h = hsum[i];
        if (h > 0.f) RL = logf(h + SELF_TERM);
        NH = nhighf[i];
    }
    if (g == 0 && tid < NCLSR) {
        const float nc = (float)cnt[tid];
        NT = nc * (nc - 1.f);
    }
    #pragma unroll
    for (int off = 32; off > 0; off >>= 1) {
        SL += __shfl_xor(SL, off); RL += __shfl_xor(RL, off);
        NH += __shfl_xor(NH, off); NT += __shfl_xor(NT, off);
    }
    __shared__ float part[4][4];
    if ((tid & 63) == 0) {
        int w = tid >> 6;
        part[w][0] = SL; part[w][1] = RL; part[w][2] = NH; part[w][3] = NT;
    }
    __syncthreads();
    if (tid == 0) {
        float sl = part[0][0] + part[1][0] + part[2][0] + part[3][0];
        float rl = part[0][1] + part[1][1] + part[2][1] + part[3][1];
        float nh = part[0][2] + part[1][2] + part[2][2] + part[3][2];
        float nt = part[0][3] + part[1][3] + part[2][3] + part[3][3];
        atomicAdd(&scal[1], sl);
        atomicAdd(&scal[2], rl);
        atomicAdd(&scal[3], nh);
        if (g == 0) atomicAdd(&scal[4], nt);
        __threadfence();
        const int ticket = atomicAdd((int*)(scal + 5), 1);
        if (ticket == 63) {
            const float SLt = atomicAdd(&scal[1], 0.f);
            const float RLt = atomicAdd(&scal[2], 0.f);
            const float NHt = atomicAdd(&scal[3], 0.f);
            const float NTt = atomicAdd(&scal[4], 0.f);
            const float pos = atomicAdd(&scal[0], 0.f) * INV_T;
            const float scl   = (NTt > 0.f) ? (SLt - pos) / NTt : 0.f;
            const float relax = (NHt > 0.f) ? RLt / NHt : 0.f;
            out[0] = scl + relax;
        }
    }
}

extern "C" void kernel_launch(void* const* d_in, const int* in_sizes, int n_in,
                              void* d_out, int out_size, void* d_ws, size_t ws_size,
                              hipStream_t stream) {
    const float* feat  = (const float*)d_in[0];
    const int* labels  = (const int*)d_in[1];
    float* out = (float*)d_out;

    char* ws = (char*)d_ws;
    unsigned short* fb = (unsigned short*)ws;                                // 4 MB
    float* Q      = (float*)(ws + (size_t)NB * ND * sizeof(unsigned short)); // 2 MB
    float* hsum   = Q + 64 * 64 * 128;
    float* nhighf = hsum + NB;
    float* scal   = nhighf + NB;          // 6 floats: possum,SL,RL,NH,NT,done

    normalize_kernel<<<NB / 4, 256, 0, stream>>>(feat, fb, hsum, nhighf, scal);
    sim_kernel<<<2080, 512, 0, stream>>>(fb, labels, Q, hsum, nhighf, scal);
    finalize_kernel<<<64, 256, 0, stream>>>(Q, hsum, nhighf, labels, scal, out);
}

// Round 12
// 118.962 us; speedup vs baseline: 1.5386x; 1.0265x over previous
//
#include <hip/hip_runtime.h>
#include <hip/hip_bf16.h>
#include <math.h>

typedef short bf16x8 __attribute__((ext_vector_type(8)));   // 8 bf16 in 4 VGPRs
typedef float f32x16 __attribute__((ext_vector_type(16)));  // 32x32 MFMA acc

#define NB 8192
#define ND 256
#define NCLSR 100         // label values 0..99
#define BK 64             // K-chunk staged in LDS per iteration
#define ES 136            // padded E row stride (bf16): 272 B = 17*16 -> 16B-aligned rows
#define INV_T 20.0f       // 1/TEMPERATURE
#define LOG2E_T 28.853900817779268f   // 20*log2(e): exp(20x) = 2^(x*this)
#define HI_THR 1.2026042e6f           // exp(14)
#define SELF_TERM 4.85165195e8f       // exp(20)

// scal[] layout: [0]=possum [1]=SL [2]=RL [3]=NH [4]=NT [5]=done-counter(int)

// ---------------- Kernel 1: row L2-normalize -> bf16 copy; zero accumulators --------
__global__ __launch_bounds__(256) void normalize_kernel(
    const float* __restrict__ feat, unsigned short* __restrict__ fb,
    float* __restrict__ hsum, float* __restrict__ nhighf,
    float* __restrict__ scal) {
    const int wave = threadIdx.x >> 6;
    const int lane = threadIdx.x & 63;
    const int row  = blockIdx.x * 4 + wave;
    float4 v = reinterpret_cast<const float4*>(feat + (size_t)row * ND)[lane];
    float ss = v.x * v.x + v.y * v.y + v.z * v.z + v.w * v.w;
    #pragma unroll
    for (int off = 32; off > 0; off >>= 1) ss += __shfl_xor(ss, off);
    const float inv = rsqrtf(ss);
    ushort4 o;
    __hip_bfloat16 h0 = __float2bfloat16(v.x * inv); o.x = *reinterpret_cast<unsigned short*>(&h0);
    __hip_bfloat16 h1 = __float2bfloat16(v.y * inv); o.y = *reinterpret_cast<unsigned short*>(&h1);
    __hip_bfloat16 h2 = __float2bfloat16(v.z * inv); o.z = *reinterpret_cast<unsigned short*>(&h2);
    __hip_bfloat16 h3 = __float2bfloat16(v.w * inv); o.w = *reinterpret_cast<unsigned short*>(&h3);
    reinterpret_cast<ushort4*>(fb + (size_t)row * ND)[lane] = o;
    if (blockIdx.x < 32) {
        const int i = (blockIdx.x << 8) + threadIdx.x;
        hsum[i] = 0.f;
        nhighf[i] = 0.f;
    } else if (blockIdx.x == 32 && threadIdx.x < 6) {
        scal[threadIdx.x] = 0.f;           // int 0 == float 0 bit pattern
    }
}

// ---------------- Kernel 2: TRIANGULAR sim tiles, MFMA row-sum epilogue ----------
// R12 changes vs R11 (all epilogue instruction-count cuts; K-loop unchanged):
//  - E buffer PADDED (stride ES=136 bf16, 16B-aligned rows) instead of XOR
//    swizzle: ds_write_b16 addresses become base + compile-time immediates
//    (no per-element XOR math); writes 2-way banked (free, m136), pass-2
//    reads 4-way on only 32 instrs.
//  - row labels: 4x int4 LDS broadcast loads per fy (8 instrs/lane) instead
//    of 32 per-element ds_read_u32.
//  - anyhigh from the lane's col-partial cs (any e>exp(14) => cs>exp(14);
//    terms positive; false positives harmless and impossible for this data).
//  - isdiag split: 2016/2080 blocks run a lean loop, no diag predication.
__global__ __launch_bounds__(512, 2) void sim_kernel(
    const unsigned short* __restrict__ fb, const int* __restrict__ labels,
    float* __restrict__ Q, float* __restrict__ hsum,
    float* __restrict__ nhighf, float* __restrict__ scal) {
    __shared__ __align__(16) unsigned short ldsU[128 * ES]; // 34816 B: staging A|B, then E
    __shared__ float ldsCol[2][128];       // [wy][local col] partial col sums
    __shared__ float ldsRowF[128];         // full row sums (from MFMA trick)
    __shared__ int   ldsLab[256];          // [0..127]=row labels, [128..255]=col labels
    __shared__ float ldsP[8];              // per-wave possum partials
    unsigned short* ldsA = ldsU;
    unsigned short* ldsB = ldsU + 128 * BK;
    unsigned short* ldsE = ldsU;           // 128 x ES bf16 overlay

    // triangular decode: t -> (bi, bj), bi >= bj  (validated R5-R11)
    const int t = blockIdx.x;
    int bi = (int)((sqrtf((float)(8 * t + 1)) - 1.0f) * 0.5f);
    while ((bi + 1) * (bi + 2) / 2 <= t) ++bi;
    while (bi * (bi + 1) / 2 > t) --bi;
    const int bj = t - bi * (bi + 1) / 2;
    const int I0 = bi << 7;
    const int J0 = bj << 7;
    const bool isdiag = (bi == bj);

    const int tid  = threadIdx.x;
    const int wave = tid >> 6;
    const int lane = tid & 63;
    const int wy = wave >> 2;              // 0..1 : row half
    const int wx = wave & 3;               // 0..3 : col quarter
    const int l31  = lane & 31;
    const int half = lane >> 5;

    if (tid < 128) ldsLab[tid] = labels[I0 + tid];
    else if (tid < 256) ldsLab[tid] = labels[J0 + tid - 128];

    int offRC[2];
    #pragma unroll
    for (int c = 0; c < 2; ++c) {
        const int Lg = (c << 6) + lane;
        const int row_loc = (wave << 4) + (Lg >> 3);
        const int g = (Lg & 7) ^ ((Lg >> 3) & 7);
        offRC[c] = row_loc * ND + (g << 3);
    }
    const unsigned short* baseA = fb + (size_t)I0 * ND;
    const unsigned short* baseB = fb + (size_t)J0 * ND;

    f32x16 acc[2];
    #pragma unroll
    for (int fy = 0; fy < 2; ++fy)
        #pragma unroll
        for (int e = 0; e < 16; ++e) acc[fy][e] = 0.f;

    for (int kk = 0; kk < ND; kk += BK) {
        __syncthreads();                   // protect LDS from prior-iter readers
        #pragma unroll
        for (int c = 0; c < 2; ++c) {
            __builtin_amdgcn_global_load_lds(
                (const __attribute__((address_space(1))) void*)(baseA + offRC[c] + kk),
                (__attribute__((address_space(3))) void*)(ldsA + (wave << 10) + (c << 9)),
                16, 0, 0);
            __builtin_amdgcn_global_load_lds(
                (const __attribute__((address_space(1))) void*)(baseB + offRC[c] + kk),
                (__attribute__((address_space(3))) void*)(ldsB + (wave << 10) + (c << 9)),
                16, 0, 0);
        }
        __syncthreads();                   // staging visible

        #pragma unroll
        for (int s = 0; s < 4; ++s) {      // four k-steps of 16 within BK=64
            const int gp = ((s << 1) + half) ^ (l31 & 7);
            const int rowB = (wx << 5) + l31;
            bf16x8 b = *reinterpret_cast<const bf16x8*>(ldsB + rowB * BK + (gp << 3));
            bf16x8 a[2];
            #pragma unroll
            for (int fy = 0; fy < 2; ++fy) {
                const int rowA = (wy << 6) + (fy << 5) + l31;
                a[fy] = *reinterpret_cast<const bf16x8*>(ldsA + rowA * BK + (gp << 3));
            }
            #pragma unroll
            for (int fy = 0; fy < 2; ++fy)
                acc[fy] = __builtin_amdgcn_mfma_f32_32x32x16_bf16(a[fy], b, acc[fy], 0, 0, 0);
        }
    }
    __syncthreads();                       // all K-loop LDS reads done before E overwrite

    // Epilogue pass 1: exp, col partials, possum, E -> padded LDS.
    // C/D layout (m74/m101-verified): col = l31, row = (reg&3)+8*(reg>>2)+4*half.
    const int ccol = (wx << 5) + l31;      // block-local col
    const int lcol = ldsLab[128 + ccol];
    // per-lane E base: rows offset by 4*half, col = ccol
    unsigned short* ePtr = ldsE + (half << 2) * ES + ccol;

    float cs = 0.f;                        // this lane's col partial (64 rows)
    float pp = 0.f;                        // positive-pair cos partial

    if (!isdiag) {                         // lean path (2016 blocks)
        #pragma unroll
        for (int fy = 0; fy < 2; ++fy) {
            const int rbase = (wy << 6) + (fy << 5) + (half << 2);
            int4 lr[4];
            #pragma unroll
            for (int g = 0; g < 4; ++g)
                lr[g] = *reinterpret_cast<const int4*>(&ldsLab[rbase + (g << 3)]);
            #pragma unroll
            for (int reg = 0; reg < 16; ++reg) {
                const int g = reg >> 2, idx = reg & 3;
                const int lrow = (idx == 0) ? lr[g].x : (idx == 1) ? lr[g].y
                               : (idx == 2) ? lr[g].z : lr[g].w;
                const float a = acc[fy][reg];
                const float e = exp2f(a * LOG2E_T);
                cs += e;
                if (lcol == lrow) pp += a;
                __hip_bfloat16 h = __float2bfloat16(e);
                const int roff = (wy << 6) + (fy << 5) + idx + (g << 3); // +4*half in ePtr
                ePtr[roff * ES] = *reinterpret_cast<unsigned short*>(&h);
            }
        }
    } else {                               // careful path (64 diag blocks)
        #pragma unroll
        for (int fy = 0; fy < 2; ++fy) {
            const bool dband = (((wy << 1) + fy) == wx);
            #pragma unroll
            for (int reg = 0; reg < 16; ++reg) {
                const int rloc = (reg & 3) + ((reg >> 2) << 3) + (half << 2);
                const int row_local = (wy << 6) + (fy << 5) + rloc;
                const int lrow = ldsLab[row_local];
                const float a = acc[fy][reg];
                const bool diag_el = dband && (l31 == rloc);
                float e = exp2f(a * LOG2E_T);
                if (diag_el) e = 0.f;
                cs += e;
                if (lcol == lrow && !diag_el) pp += a;
                __hip_bfloat16 h = __float2bfloat16(e);
                ldsE[row_local * ES + ccol] = *reinterpret_cast<unsigned short*>(&h);
            }
        }
    }
    const int anyhigh = (cs > HI_THR);     // no false negatives (terms positive)
    cs += __shfl_xor(cs, 32);              // combine halves (same column)
    if (half == 0) ldsCol[wy][ccol] = cs;
    #pragma unroll
    for (int off = 32; off > 0; off >>= 1) pp += __shfl_xor(pp, off);
    if (lane == 0) ldsP[wave] = pp;

    __syncthreads();                       // E complete

    // Epilogue pass 2: row sums via MFMA (waves 0..3, rows [32w,+32)).
    // D = ones x E_B: B-frag lane n holds E[32w+n][k-chunk] -> D[.][n] =
    // rowsum(E[32w+n]), replicated across regs.
    if (wave < 4) {
        bf16x8 ones;
        #pragma unroll
        for (int j = 0; j < 8; ++j) ones[j] = (short)0x3F80;   // bf16 1.0
        f32x16 rs;
        #pragma unroll
        for (int e = 0; e < 16; ++e) rs[e] = 0.f;
        const int rE = (wave << 5) + l31;
        const unsigned short* rPtr = ldsE + rE * ES + (half << 3);
        #pragma unroll
        for (int kc = 0; kc < 8; ++kc) {
            bf16x8 bE = *reinterpret_cast<const bf16x8*>(rPtr + (kc << 4));
            rs = __builtin_amdgcn_mfma_f32_32x32x16_bf16(ones, bE, rs, 0, 0, 0);
        }
        if (half == 0) ldsRowF[rE] = rs[0];
    }
    __syncthreads();                       // ldsRowF + ldsCol ready

    if (tid < 128) {
        Q[(size_t)(bi * 64 + bj) * 128 + tid] = ldsRowF[tid];
    } else if (tid < 256 && !isdiag) {
        const int c2 = tid - 128;
        Q[(size_t)(bj * 64 + bi) * 128 + c2] = ldsCol[0][c2] + ldsCol[1][c2];
    }
    if (tid == 0) {
        const float scale = isdiag ? 1.f : 2.f;
        atomicAdd(&scal[0], (ldsP[0] + ldsP[1] + ldsP[2] + ldsP[3] +
                             ldsP[4] + ldsP[5] + ldsP[6] + ldsP[7]) * scale);
    }

    // Cold path (never taken for this data): relax-term bookkeeping.
    if (__any(anyhigh)) {
        #pragma unroll
        for (int fy = 0; fy < 2; ++fy) {
            const bool dband = isdiag && (((wy << 1) + fy) == wx);
            #pragma unroll
            for (int reg = 0; reg < 16; ++reg) {
                const int rloc = (reg & 3) + ((reg >> 2) << 3) + (half << 2);
                const int row_local = (wy << 6) + (fy << 5) + rloc;
                const int lrow = ldsLab[row_local];
                const float a = acc[fy][reg];
                const bool diag_el = dband && (l31 == rloc);
                if (a > 0.7f && lcol == lrow && !diag_el) {
                    const float e2 = exp2f(a * LOG2E_T);
                    atomicAdd(&hsum[I0 + row_local], e2);
                    atomicAdd(&nhighf[I0 + row_local], 1.f);
                    if (!isdiag) {
                        atomicAdd(&hsum[J0 + ccol], e2);
                        atomicAdd(&nhighf[J0 + ccol], 1.f);
                    }
                }
            }
        }
    }
}

// ---------------- Kernel 3: fused Q-reduce + finalize (64 blocks) ----------------
__global__ __launch_bounds__(256) void finalize_kernel(
    const float* __restrict__ Q, const float* __restrict__ hsum,
    const float* __restrict__ nhighf, const int* __restrict__ labels,
    float* __restrict__ scal, float* __restrict__ out) {
    const int g = blockIdx.x;
    const int tid = threadIdx.x;
    __shared__ int cnt[128];
    if (tid < 128) cnt[tid] = 0;
    __syncthreads();
    for (int i = tid; i < NB; i += 256)
        atomicAdd(&cnt[labels[i]], 1);
    const int r = tid & 127;
    const int sh = tid >> 7;
    const float* base = Q + (size_t)g * 64 * 128;
    float s = 0.f;
    #pragma unroll 8
    for (int i = 0; i < 32; ++i)
        s += base[(size_t)(sh * 32 + i) * 128 + r];
    __shared__ float red[256];
    red[tid] = s;
    __syncthreads();
    float SL = 0.f, RL = 0.f, NH = 0.f, NT = 0.f;
    if (tid < 128) {
        const float denom = red[tid] + red[tid + 128];
        const int i = (g << 7) + tid;
        const float np = (float)(cnt[labels[i]] - 1);
        SL = np * logf(denom + 1e-8f);
        const float h = hsum[i];
        if (h > 0.f) RL = logf(h + SELF_TERM);
        NH = nhighf[i];
    }
    if (g == 0 && tid < NCLSR) {
        const float nc = (float)cnt[tid];
        NT = nc * (nc - 1.f);
    }
    #pragma unroll
    for (int off = 32; off > 0; off >>= 1) {
        SL += __shfl_xor(SL, off); RL += __shfl_xor(RL, off);
        NH += __shfl_xor(NH, off); NT += __shfl_xor(NT, off);
    }
    __shared__ float part[4][4];
    if ((tid & 63) == 0) {
        int w = tid >> 6;
        part[w][0] = SL; part[w][1] = RL; part[w][2] = NH; part[w][3] = NT;
    }
    __syncthreads();
    if (tid == 0) {
        float sl = part[0][0] + part[1][0] + part[2][0] + part[3][0];
        float rl = part[0][1] + part[1][1] + part[2][1] + part[3][1];
        float nh = part[0][2] + part[1][2] + part[2][2] + part[3][2];
        float nt = part[0][3] + part[1][3] + part[2][3] + part[3][3];
        atomicAdd(&scal[1], sl);
        atomicAdd(&scal[2], rl);
        atomicAdd(&scal[3], nh);
        if (g == 0) atomicAdd(&scal[4], nt);
        __threadfence();
        const int ticket = atomicAdd((int*)(scal + 5), 1);
        if (ticket == 63) {
            const float SLt = atomicAdd(&scal[1], 0.f);
            const float RLt = atomicAdd(&scal[2], 0.f);
            const float NHt = atomicAdd(&scal[3], 0.f);
            const float NTt = atomicAdd(&scal[4], 0.f);
            const float pos = atomicAdd(&scal[0], 0.f) * INV_T;
            const float scl   = (NTt > 0.f) ? (SLt - pos) / NTt : 0.f;
            const float relax = (NHt > 0.f) ? RLt / NHt : 0.f;
            out[0] = scl + relax;
        }
    }
}

extern "C" void kernel_launch(void* const* d_in, const int* in_sizes, int n_in,
                              void* d_out, int out_size, void* d_ws, size_t ws_size,
                              hipStream_t stream) {
    const float* feat  = (const float*)d_in[0];
    const int* labels  = (const int*)d_in[1];
    float* out = (float*)d_out;

    char* ws = (char*)d_ws;
    unsigned short* fb = (unsigned short*)ws;                                // 4 MB
    float* Q      = (float*)(ws + (size_t)NB * ND * sizeof(unsigned short)); // 2 MB
    float* hsum   = Q + 64 * 64 * 128;
    float* nhighf = hsum + NB;
    float* scal   = nhighf + NB;          // 6 floats: possum,SL,RL,NH,NT,done

    normalize_kernel<<<NB / 4, 256, 0, stream>>>(feat, fb, hsum, nhighf, scal);
    sim_kernel<<<2080, 512, 0, stream>>>(fb, labels, Q, hsum, nhighf, scal);
    finalize_kernel<<<64, 256, 0, stream>>>(Q, hsum, nhighf, labels, scal, out);
}